// Round 3
// baseline (132.723 us; speedup 1.0000x reference)
//
#include <hip/hip_runtime.h>
#include <hip/hip_bf16.h>
#include <cstdint>

#define B_ 2048
#define N_ 4096
#define D_ 256
#define P_ 100
#define K_ 30
#define INVT 5.0f

typedef __attribute__((ext_vector_type(8))) short bf16x8;
typedef __attribute__((ext_vector_type(4))) float f32x4;
typedef __attribute__((ext_vector_type(4))) unsigned short us4;

__device__ __forceinline__ float waveReduceSum(float v) {
#pragma unroll
  for (int off = 32; off > 0; off >>= 1) v += __shfl_xor(v, off, 64);
  return v;
}

__device__ __forceinline__ unsigned short f2bf(float f) {
  __hip_bfloat16 h = __float2bfloat16(f);
  return *reinterpret_cast<unsigned short*>(&h);
}
__device__ __forceinline__ float bf2f(unsigned short u) {
  return __uint_as_float(((unsigned int)u) << 16);
}

// ---- K1: block 0 = zero sums/ticket + hist/concat; 1..100 = proto_dist row; 101..612 = row-norm+pos ----
__global__ __launch_bounds__(256) void prep_kernel(
    const float* __restrict__ x, const float* __restrict__ xa, const float* __restrict__ pw,
    const int* __restrict__ hq1, const int* __restrict__ hq2, int* __restrict__ hq,
    int* __restrict__ cnt, float* __restrict__ pd, __hip_bfloat16* __restrict__ outb,
    float* __restrict__ sums) {
  __shared__ int c[P_];
  __shared__ float s4[4];
  int t = threadIdx.x, lane = t & 63, wv = t >> 6;
  int bx = blockIdx.x;
  if (bx == 0) {
    if (t < 2) sums[t] = 0.f;
    if (t == 2) ((int*)sums)[2] = 0;  // ticket
    if (t < P_) c[t] = 0;
    __syncthreads();
    for (int i = t; i < N_; i += 256) {
      int q = (i < B_) ? hq1[i] : hq2[i - B_];
      hq[i] = q;
      atomicAdd(&c[q], 1);
    }
    __syncthreads();
    if (t < P_) cnt[t] = c[t];
  } else if (bx <= P_) {
    int q = bx - 1;
    float4 aq = ((const float4*)(pw + q * D_))[lane];
    float ssq = waveReduceSum(aq.x * aq.x + aq.y * aq.y + aq.z * aq.z + aq.w * aq.w);
    float qinv = 1.f / fmaxf(sqrtf(ssq), 1e-12f);
    for (int r = wv; r < P_; r += 4) {
      float4 b = ((const float4*)(pw + r * D_))[lane];
      float s = aq.x * b.x + aq.y * b.y + aq.z * b.z + aq.w * b.w;
      float n = b.x * b.x + b.y * b.y + b.z * b.z + b.w * b.w;
      s = waveReduceSum(s);
      n = waveReduceSum(n);
      if (lane == 0) pd[q * P_ + r] = s * qinv / fmaxf(sqrtf(n), 1e-12f);
    }
  } else {
    int i = (bx - 101) * 4 + wv;
    float4 a = ((const float4*)(x + i * D_))[lane];
    float ss = waveReduceSum(a.x * a.x + a.y * a.y + a.z * a.z + a.w * a.w);
    float inv1 = 1.f / fmaxf(sqrtf(ss), 1e-12f);
    float o1x = a.x * inv1, o1y = a.y * inv1, o1z = a.z * inv1, o1w = a.w * inv1;
    us4 p1; p1[0] = f2bf(o1x); p1[1] = f2bf(o1y); p1[2] = f2bf(o1z); p1[3] = f2bf(o1w);
    ((us4*)(outb + i * D_))[lane] = p1;
    float4 b = ((const float4*)(xa + i * D_))[lane];
    float ss2 = waveReduceSum(b.x * b.x + b.y * b.y + b.z * b.z + b.w * b.w);
    float inv2 = 1.f / fmaxf(sqrtf(ss2), 1e-12f);
    float o2x = b.x * inv2, o2y = b.y * inv2, o2z = b.z * inv2, o2w = b.w * inv2;
    us4 p2; p2[0] = f2bf(o2x); p2[1] = f2bf(o2y); p2[2] = f2bf(o2z); p2[3] = f2bf(o2w);
    ((us4*)(outb + (B_ + i) * D_))[lane] = p2;
    float d = waveReduceSum(o1x * o2x + o1y * o2y + o1z * o2z + o1w * o2w);
    if (lane == 0) s4[wv] = d;
    __syncthreads();
    if (t == 0) atomicAdd(&sums[1], s4[0] + s4[1] + s4[2] + s4[3]);
  }
}

// ---- K2: per-row Gtab[i][p] (bf16) = member ? reweight : 0 ----
__global__ void gtab_kernel(const int* __restrict__ hq, const int* __restrict__ cnt,
                            const float* __restrict__ pd, const int* __restrict__ nq1,
                            const int* __restrict__ nq2, unsigned short* __restrict__ gtabh) {
  __shared__ unsigned char memb[4][104];
  int wv = threadIdx.x >> 6, lane = threadIdx.x & 63;
  int i = blockIdx.x * 4 + wv;
  int q = hq[i];
  if (lane < 52) { memb[wv][lane * 2] = 0; memb[wv][lane * 2 + 1] = 0; }
  __syncthreads();
  const int* nrow = (i < B_) ? (nq1 + i * K_) : (nq2 + (i - B_) * K_);
  if (lane < K_) memb[wv][nrow[lane]] = 1;
  __syncthreads();

  int p0 = lane, p1 = lane + 64;
  bool has1 = (p1 < P_);
  float v0 = pd[q * P_ + p0];
  int m0 = cnt[p0] - (p0 == q ? 1 : 0);
  float v1 = 0.f; int m1 = 0;
  if (has1) { v1 = pd[q * P_ + p1]; m1 = cnt[p1] - (p1 == q ? 1 : 0); }

  float mn = 1e30f, mx = -1e30f;
  if (m0 > 0) { mn = fminf(mn, v0); mx = fmaxf(mx, v0); }
  if (has1 && m1 > 0) { mn = fminf(mn, v1); mx = fmaxf(mx, v1); }
#pragma unroll
  for (int off = 32; off > 0; off >>= 1) {
    mn = fminf(mn, __shfl_xor(mn, off, 64));
    mx = fmaxf(mx, __shfl_xor(mx, off, 64));
  }
  float rmin = fminf(0.f, mn);
  float rmax = fmaxf(rmin, mx);
  float inv = 1.f / (rmax - rmin);
  float r0 = (v0 - rmin) * inv, r1 = (v1 - rmin) * inv;
  float s1 = (m0 > 0 ? (float)m0 * r0 : 0.f) + ((has1 && m1 > 0) ? (float)m1 * r1 : 0.f);
  s1 = waveReduceSum(s1);
  float mu = s1 / (float)N_;
  float ss = (m0 > 0 ? (float)m0 * (r0 - mu) * (r0 - mu) : 0.f) +
             ((has1 && m1 > 0) ? (float)m1 * (r1 - mu) * (r1 - mu) : 0.f);
  ss = waveReduceSum(ss);
  ss += mu * mu;
  float var = ss / (float)(N_ - 1);
  float i2v = 1.f / (2.f * var);
  float g0 = memb[wv][p0] ? __expf((r0 - mu) * (r0 - mu) * i2v) : 0.f;
  gtabh[i * P_ + p0] = f2bf(g0);
  if (has1) {
    float g1 = memb[wv][p1] ? __expf((r1 - mu) * (r1 - mu) * i2v) : 0.f;
    gtabh[i * P_ + p1] = f2bf(g1);
  }
}

// ---- K3: full-matrix masked-weighted exp-sum + fused finish ----
__device__ __forceinline__ void gload16(void* ldsdst, const void* gsrc) {
  __builtin_amdgcn_global_load_lds(
      (const __attribute__((address_space(1))) unsigned int*)gsrc,
      (__attribute__((address_space(3))) unsigned int*)ldsdst, 16, 0, 0);
}

__global__ __launch_bounds__(512, 4) void tot_kernel(
    const __hip_bfloat16* __restrict__ outb, const unsigned short* __restrict__ gtabh,
    const int* __restrict__ hq, float* __restrict__ sums, float* __restrict__ out) {
  __shared__ __align__(16) char lds[65536];  // A:[0,32K) B:[32K,64K), 256B rows
  __shared__ float s8[8];
  const int tid = threadIdx.x, lane = tid & 63, wid = tid >> 6;
  const int i0 = blockIdx.y * 128, j0 = blockIdx.x * 128;
  const int wr = wid >> 2, wc = wid & 3;

  f32x4 acc[4][2] = {};

  const int wseg = wid & 3;
  const bool isB = (wid >= 4);
  const int growbase = isB ? j0 : i0;
  char* panel = lds + (isB ? 32768 : 0);

  for (int kk = 0; kk < 2; ++kk) {
#pragma unroll
    for (int it = 0; it < 8; ++it) {
      int rbase = wseg * 32 + it * 4;
      int row = rbase + (lane >> 4);
      int c = lane & 15;
      int src = (growbase + row) * D_ + kk * 128 + ((c ^ (row & 7)) * 8);
      gload16(panel + rbase * 256, outb + src);
    }
    __syncthreads();
#pragma unroll
    for (int ks = 0; ks < 4; ++ks) {
      bf16x8 af[4], bfr[2];
#pragma unroll
      for (int m = 0; m < 4; ++m) {
        int row = wr * 64 + m * 16 + (lane & 15);
        int off = row * 256 + ((((ks << 2) + (lane >> 4)) ^ (row & 7)) << 4);
        af[m] = *(const bf16x8*)(lds + off);
      }
#pragma unroll
      for (int n = 0; n < 2; ++n) {
        int row = wc * 32 + n * 16 + (lane & 15);
        int off = 32768 + row * 256 + ((((ks << 2) + (lane >> 4)) ^ (row & 7)) << 4);
        bfr[n] = *(const bf16x8*)(lds + off);
      }
#pragma unroll
      for (int m = 0; m < 4; ++m)
#pragma unroll
        for (int n = 0; n < 2; ++n)
          acc[m][n] = __builtin_amdgcn_mfma_f32_16x16x32_bf16(af[m], bfr[n], acc[m][n], 0, 0, 0);
    }
    __syncthreads();  // all LDS reads done before restage / epilogue reuse
  }

  // ---- epilogue: stage G^T rows (bf16, padded 132) + hq_j into LDS ----
  unsigned short* gaT = (unsigned short*)lds;  // [P_][132]
  int* hqj = (int*)(lds + 26624);              // [128]
  for (int idx = tid; idx < 128 * P_; idx += 512) {
    int r = idx / P_, c = idx - r * P_;
    gaT[c * 132 + r] = gtabh[(i0 + r) * P_ + c];
  }
  if (tid < 128) hqj[tid] = hq[j0 + tid];
  __syncthreads();

  const int jl0 = wc * 32 + (lane & 15);
  const int jl1 = jl0 + 16;
  const int hj0 = hqj[jl0], hj1 = hqj[jl1];
  const int jg0 = j0 + jl0, jg1 = j0 + jl1;
  float local = 0.f;
#pragma unroll
  for (int m = 0; m < 4; ++m) {
    int ilb = wr * 64 + m * 16 + ((lane >> 4) << 2);
    us4 w0 = *(const us4*)(gaT + hj0 * 132 + ilb);
    us4 w1 = *(const us4*)(gaT + hj1 * 132 + ilb);
#pragma unroll
    for (int r = 0; r < 4; ++r) {
      int ig = i0 + ilb + r;
      float e0 = __expf(acc[m][0][r] * INVT);
      float e1 = __expf(acc[m][1][r] * INVT);
      local += (ig != jg0) ? bf2f(w0[r]) * e0 : 0.f;
      local += (ig != jg1) ? bf2f(w1[r]) * e1 : 0.f;
    }
  }
  local = waveReduceSum(local);
  if (lane == 0) s8[wid] = local;
  __syncthreads();
  if (tid == 0) {
    float t = 0.f;
#pragma unroll
    for (int w = 0; w < 8; ++w) t += s8[w];
    atomicAdd(&sums[0], t);
    __threadfence();
    int* ticket = (int*)sums + 2;
    int done = atomicAdd(ticket, 1);
    if (done == 1023) {
      float tot = atomicAdd(&sums[0], 0.f);   // coherent read
      float pos = atomicAdd(&sums[1], 0.f);
      out[0] = logf(tot) - pos * (INVT / (float)B_);
    }
  }
}

extern "C" void kernel_launch(void* const* d_in, const int* in_sizes, int n_in,
                              void* d_out, int out_size, void* d_ws, size_t ws_size,
                              hipStream_t stream) {
  const float* x   = (const float*)d_in[0];
  const float* xa  = (const float*)d_in[1];
  const float* pw  = (const float*)d_in[2];
  const int* hq1   = (const int*)d_in[3];
  const int* hq2   = (const int*)d_in[4];
  const int* nq1   = (const int*)d_in[5];
  const int* nq2   = (const int*)d_in[6];
  float* out = (float*)d_out;

  char* ws = (char*)d_ws;
  __hip_bfloat16* outb  = (__hip_bfloat16*)(ws);               // 2,097,152 B
  unsigned short* gtabh = (unsigned short*)(ws + 2097152);     // 819,200 B
  float* pd    = (float*)(ws + 2916352);                       // 40,000 B
  int*   hq    = (int*)  (ws + 2956800);                       // 16,384 B
  int*   cnt   = (int*)  (ws + 2973184);                       // 400 B
  float* sums  = (float*)(ws + 2973696);                       // 16 B (2 accum + ticket)

  prep_kernel<<<613, 256, 0, stream>>>(x, xa, pw, hq1, hq2, hq, cnt, pd, outb, sums);
  gtab_kernel<<<N_ / 4, 256, 0, stream>>>(hq, cnt, pd, nq1, nq2, gtabh);
  tot_kernel<<<dim3(32, 32), 512, 0, stream>>>(outb, gtabh, hq, sums, out);
}